// Round 11
// baseline (368.457 us; speedup 1.0000x reference)
//
#include <hip/hip_runtime.h>
#include <hip/hip_fp16.h>
#include <math.h>

// Problem constants (fixed by reference setup_inputs)
#define BB 4096
#define LL 16
#define DD 512

#define LOG2E_F  1.4426950408889634f
#define LN2_F    0.6931471805599453f
#define LOG2PI_F 1.8378770664093453f

// f16-Schraudolph via pknorm: coefs scaled by S=1024/65535 with offset OFFC
// folded in. pknorm_u16(lp_n) = round(1024*(lp2+OFFC)) = f16 bits of
// 2^(lp2 + OFFC-15) (OFFC=23 -> 2^(lp2+8)); negatives clamp to 0.
#define OFFC     22.942540f
#define SCALE23  8388608.0f
#define BIASF    126.94269504f

#if __has_builtin(__builtin_amdgcn_exp2f)
#define EXP2(x) __builtin_amdgcn_exp2f(x)
#else
#define EXP2(x) exp2f(x)
#endif
#if __has_builtin(__builtin_amdgcn_logf)
#define LOG2(x) __builtin_amdgcn_logf(x)
#else
#define LOG2(x) log2f(x)
#endif

// ws float layout (nc = 128):
//   coef    [0      , 196608)   4096 j * 48  (A''[16] B''[16] C''[16], S-scaled)
//   rp      [196608 , 198656)   2048 recon block partials (pre-scaled)
//   klp     [198656 , 198912)   256 KL block partials (pre-scaled)
//   reduced [198912 , 268544)   17 * 4096  (k-major; k=16 is joint)
//   partial [268544 , +nc*17*4096)  tc partials, [(c*17+k)*4096 + i]
#define COEF_F   0
#define RP_F     196608
#define KLP_F    198656
#define RED_F    198912
#define PART_F   268544

// Block-level sum reduction; result valid on thread 0. Re-entrant.
__device__ __forceinline__ float block_reduce(float v) {
  __shared__ float sm[4];
  __syncthreads();  // protect sm reuse across calls
#pragma unroll
  for (int off = 32; off; off >>= 1) v += __shfl_xor(v, off);
  if ((threadIdx.x & 63) == 0) sm[threadIdx.x >> 6] = v;
  __syncthreads();
  if (threadIdx.x == 0) v = (sm[0] + sm[1]) + (sm[2] + sm[3]);
  return v;
}

// ---------------------------------------------------------------------------
// Kernel A: recon partials (grid-stride) + coef prep + KL partials + out zero.
// ---------------------------------------------------------------------------
__global__ __launch_bounds__(256) void prep_recon_kernel(
    const float4* __restrict__ data4, const float4* __restrict__ recon4,
    const float* __restrict__ zm, const float* __restrict__ zlv,
    float* __restrict__ coef, float* __restrict__ rp,
    float* __restrict__ klp, float* __restrict__ out) {
  const int tid = threadIdx.x;
  const int b = blockIdx.x;

  if (b == 1024 && tid == 0) out[0] = 0.0f;  // consumed by final_kernel later

  {
    const int n4 = (BB * DD) / 4;
    int stride = gridDim.x * 256;
    float s = 0.0f;
    for (int k = b * 256 + tid; k < n4; k += stride) {
      float4 a = data4[k];
      float4 r = recon4[k];
      s += (fabsf(a.x - r.x) + fabsf(a.y - r.y)) +
           (fabsf(a.z - r.z) + fabsf(a.w - r.w));
    }
    float t = block_reduce(s);
    if (tid == 0) rp[b] = t * (1.0f / (float)(BB * DD));
  }

  if (b < 256) {
    const float S = 1024.0f / 65535.0f;
    int idx = b * 256 + tid;
    int j = idx >> 4;
    int l = idx & 15;
    float m = zm[idx];
    float lv = zlv[idx];
    float inv = EXP2(-lv * LOG2E_F);           // e^{-lv}
    float a = -0.5f * LOG2E_F * inv;
    float c2 = -0.5f * LOG2E_F * (lv + LOG2PI_F);
    coef[j * 48 + l]      = a * S;
    coef[j * 48 + 16 + l] = -2.0f * a * m * S;
    coef[j * 48 + 32 + l] = (fmaf(a, m * m, c2) + OFFC) * S;

    float kls = m * m + EXP2(lv * LOG2E_F) - lv - 1.0f;
    float s = block_reduce(kls);
    if (tid == 0) klp[b] = s * (0.5f / (float)BB);
  }
}

// ---------------------------------------------------------------------------
// Kernel B: TC partial sums. R10 numerics unchanged; coef now staged in LDS
// once per block (6 KB) and read via wave-uniform ds_read_b128 (broadcast,
// VGPR-addressed) instead of s_load — removes the SGPR=64 prefetch ceiling
// that exposed scalar-load latency every j-iteration.
// ---------------------------------------------------------------------------
template <int CHUNK>
__global__ __launch_bounds__(256, 8) void tc_kernel(
    const float* __restrict__ z, const float* __restrict__ coef,
    float* __restrict__ partial) {
  __shared__ float lcoef[CHUNK * 48];
  const int tid = threadIdx.x;
  const int i = blockIdx.x * 256 + tid;  // this lane's row
  const int j0 = blockIdx.y * CHUNK;
  // w = js*65535*8192 - 2^23*(16*OFFC - BIASF)  ==  2^23*(sum_l lp2 + BIASF)
  const float JMUL = 65535.0f * 8192.0f;
  const float JK   = -SCALE23 * (16.0f * OFFC - BIASF);

  // Stage this block's coef chunk into LDS (coalesced float4 loads).
  {
    const float4* g4 = (const float4*)(coef + (size_t)j0 * 48);
    float4* l4 = (float4*)lcoef;
#pragma unroll
    for (int t = tid; t < (CHUNK * 48) / 4; t += 256) l4[t] = g4[t];
  }

  float zv[16];
  const float4* zp = (const float4*)(z + i * 16);
#pragma unroll
  for (int q = 0; q < 4; ++q) {
    float4 v = zp[q];
    zv[4 * q] = v.x; zv[4 * q + 1] = v.y; zv[4 * q + 2] = v.z; zv[4 * q + 3] = v.w;
  }

  union HU { unsigned u; __half2 h; };
  __half2 accH[8];
#pragma unroll
  for (int p = 0; p < 8; ++p) { HU t; t.u = 0u; accH[p] = t.h; }
  float accJ = 0.0f;

  __syncthreads();

  const float* cp = lcoef;
#pragma unroll 4
  for (int j = 0; j < CHUNK; ++j) {
    float A[16], Bq[16], Cq[16];
#pragma unroll
    for (int q = 0; q < 4; ++q) {
      float4 va = *(const float4*)(cp + 4 * q);           // ds_read_b128
      float4 vb = *(const float4*)(cp + 16 + 4 * q);
      float4 vc = *(const float4*)(cp + 32 + 4 * q);
      A[4 * q] = va.x;  A[4 * q + 1] = va.y;  A[4 * q + 2] = va.z;  A[4 * q + 3] = va.w;
      Bq[4 * q] = vb.x; Bq[4 * q + 1] = vb.y; Bq[4 * q + 2] = vb.z; Bq[4 * q + 3] = vb.w;
      Cq[4 * q] = vc.x; Cq[4 * q + 1] = vc.y; Cq[4 * q + 2] = vc.z; Cq[4 * q + 3] = vc.w;
    }

    float lp[16];
#pragma unroll
    for (int l = 0; l < 16; ++l)
      lp[l] = fmaf(fmaf(A[l], zv[l], Bq[l]), zv[l], Cq[l]);

#pragma unroll
    for (int p = 0; p < 8; ++p) {
      HU t;
      asm("v_cvt_pknorm_u16_f32 %0, %1, %2"
          : "=v"(t.u) : "v"(lp[2 * p]), "v"(lp[2 * p + 1]));
      accH[p] = __hadd2(accH[p], t.h);
    }

    // joint: tree-sum of raw lp_n (includes deep-underflow negatives)
    float s0 = (lp[0] + lp[1]) + (lp[2] + lp[3]);
    float s1 = (lp[4] + lp[5]) + (lp[6] + lp[7]);
    float s2 = (lp[8] + lp[9]) + (lp[10] + lp[11]);
    float s3 = (lp[12] + lp[13]) + (lp[14] + lp[15]);
    float js = (s0 + s1) + (s2 + s3);
    float w = fmaf(js, JMUL, JK);
    unsigned u;
    asm("v_cvt_u32_f32 %0, %1" : "=v"(u) : "v"(w));  // negatives saturate to 0
    accJ += __uint_as_float(u);
    cp += 48;
  }

  float* base = partial + ((size_t)blockIdx.y * 17) * BB + i;
#pragma unroll
  for (int p = 0; p < 8; ++p) {
    // accH halves hold sum_j 2^(lp2+8); 2^-8 rescale to true exp2 sums
    base[(size_t)(2 * p) * BB]     = 0.00390625f * __low2float(accH[p]);
    base[(size_t)(2 * p + 1) * BB] = 0.00390625f * __high2float(accH[p]);
  }
  base[(size_t)16 * BB] = accJ;
}

// ---------------------------------------------------------------------------
// Kernel C: reduce partials over chunks. grid (16, 17) = 272 blocks.
// ---------------------------------------------------------------------------
__global__ __launch_bounds__(256) void reduce_kernel(
    const float* __restrict__ partial, float* __restrict__ reduced, int nc) {
  const int i = blockIdx.x * 256 + threadIdx.x;
  const int k = blockIdx.y;
  const float* p = partial + (size_t)k * BB + i;
  const size_t cstride = (size_t)17 * BB;
  float s0 = 0.0f, s1 = 0.0f, s2 = 0.0f, s3 = 0.0f;
  int c = 0;
  for (; c + 4 <= nc; c += 4) {
    s0 += p[(size_t)(c + 0) * cstride];
    s1 += p[(size_t)(c + 1) * cstride];
    s2 += p[(size_t)(c + 2) * cstride];
    s3 += p[(size_t)(c + 3) * cstride];
  }
  for (; c < nc; ++c) s0 += p[(size_t)c * cstride];
  reduced[(size_t)k * BB + i] = (s0 + s1) + (s2 + s3);
}

// ---------------------------------------------------------------------------
// Kernel D: logs + fold recon/KL partials into out[0] (zeroed by kernel A).
// ---------------------------------------------------------------------------
__global__ __launch_bounds__(256) void final_kernel(
    const float* __restrict__ reduced, const float* __restrict__ rp,
    const float* __restrict__ klp, float* __restrict__ out) {
  const int tid = threadIdx.x;
  const int i = blockIdx.x * 256 + tid;
  float lg = LOG2(reduced[(size_t)16 * BB + i]);  // log2 S_joint
#pragma unroll
  for (int k = 0; k < 16; ++k) lg -= LOG2(reduced[(size_t)k * BB + i]);
  float t = lg * (LN2_F / (float)BB);
  if (blockIdx.x == 0) {
#pragma unroll
    for (int q = 0; q < 8; ++q) t += rp[tid + 256 * q];  // 2048 recon partials
    t += klp[tid];
  }
  float s = block_reduce(t);
  if (tid == 0) atomicAdd(out, s);
}

extern "C" void kernel_launch(void* const* d_in, const int* in_sizes, int n_in,
                              void* d_out, int out_size, void* d_ws, size_t ws_size,
                              hipStream_t stream) {
  const float* data  = (const float*)d_in[0];
  const float* recon = (const float*)d_in[1];
  const float* z     = (const float*)d_in[2];
  const float* zm    = (const float*)d_in[3];
  const float* zlv   = (const float*)d_in[4];
  float* out = (float*)d_out;
  float* ws  = (float*)d_ws;

  // nc=128 (CHUNK=32) if the partial buffer fits, else nc=64 (CHUNK=64).
  int nc = 128;
  if (((size_t)PART_F + (size_t)nc * 17 * BB) * 4 > ws_size) nc = 64;

  float* coef = ws + COEF_F;
  float* rp   = ws + RP_F;
  float* klp  = ws + KLP_F;
  float* red  = ws + RED_F;
  float* part = ws + PART_F;

  hipLaunchKernelGGL(prep_recon_kernel, dim3(2048), dim3(256), 0, stream,
                     reinterpret_cast<const float4*>(data),
                     reinterpret_cast<const float4*>(recon),
                     zm, zlv, coef, rp, klp, out);
  if (nc == 128) {
    hipLaunchKernelGGL(tc_kernel<32>, dim3(16, 128), dim3(256), 0, stream,
                       z, coef, part);
  } else {
    hipLaunchKernelGGL(tc_kernel<64>, dim3(16, 64), dim3(256), 0, stream,
                       z, coef, part);
  }
  hipLaunchKernelGGL(reduce_kernel, dim3(BB / 256, 17), dim3(256), 0, stream,
                     part, red, nc);
  hipLaunchKernelGGL(final_kernel, dim3(BB / 256), dim3(256), 0, stream,
                     red, rp, klp, out);
}

// Round 12
// 121.346 us; speedup vs baseline: 3.0364x; 3.0364x over previous
//
#include <hip/hip_runtime.h>
#include <hip/hip_fp16.h>
#include <math.h>

// Problem constants (fixed by reference setup_inputs)
#define BB 4096
#define LL 16
#define DD 512

#define LOG2E_F  1.4426950408889634f
#define LN2_F    0.6931471805599453f
#define LOG2PI_F 1.8378770664093453f

// f16-Schraudolph via pknorm: coefs scaled by S=1024/65535 with offset OFFC
// folded in. pknorm_u16(lp_n) = round(1024*(lp2+OFFC)) = f16 bits of
// 2^(lp2 + OFFC-15) (OFFC=23 -> 2^(lp2+8)); negatives clamp to 0.
#define OFFC     22.942540f
#define SCALE23  8388608.0f
#define BIASF    126.94269504f

#if __has_builtin(__builtin_amdgcn_exp2f)
#define EXP2(x) __builtin_amdgcn_exp2f(x)
#else
#define EXP2(x) exp2f(x)
#endif
#if __has_builtin(__builtin_amdgcn_logf)
#define LOG2(x) __builtin_amdgcn_logf(x)
#else
#define LOG2(x) log2f(x)
#endif

// ws float layout (nc = 128):
//   coef    [0      , 196608)   4096 j * 48  (A''[16] B''[16] C''[16], S-scaled)
//   rp      [196608 , 198656)   2048 recon block partials (pre-scaled)
//   klp     [198656 , 198912)   256 KL block partials (pre-scaled)
//   reduced [198912 , 268544)   17 * 4096  (k-major; k=16 is joint)
//   partial [268544 , +nc*17*4096)  tc partials, [(c*17+k)*4096 + i]
#define COEF_F   0
#define RP_F     196608
#define KLP_F    198656
#define RED_F    198912
#define PART_F   268544

// Block-level sum reduction; result valid on thread 0. Re-entrant.
__device__ __forceinline__ float block_reduce(float v) {
  __shared__ float sm[4];
  __syncthreads();  // protect sm reuse across calls
#pragma unroll
  for (int off = 32; off; off >>= 1) v += __shfl_xor(v, off);
  if ((threadIdx.x & 63) == 0) sm[threadIdx.x >> 6] = v;
  __syncthreads();
  if (threadIdx.x == 0) v = (sm[0] + sm[1]) + (sm[2] + sm[3]);
  return v;
}

// ---------------------------------------------------------------------------
// Kernel A: recon partials (grid-stride) + coef prep + KL partials + out zero.
// ---------------------------------------------------------------------------
__global__ __launch_bounds__(256) void prep_recon_kernel(
    const float4* __restrict__ data4, const float4* __restrict__ recon4,
    const float* __restrict__ zm, const float* __restrict__ zlv,
    float* __restrict__ coef, float* __restrict__ rp,
    float* __restrict__ klp, float* __restrict__ out) {
  const int tid = threadIdx.x;
  const int b = blockIdx.x;

  if (b == 1024 && tid == 0) out[0] = 0.0f;  // consumed by final_kernel later

  {
    const int n4 = (BB * DD) / 4;
    int stride = gridDim.x * 256;
    float s = 0.0f;
    for (int k = b * 256 + tid; k < n4; k += stride) {
      float4 a = data4[k];
      float4 r = recon4[k];
      s += (fabsf(a.x - r.x) + fabsf(a.y - r.y)) +
           (fabsf(a.z - r.z) + fabsf(a.w - r.w));
    }
    float t = block_reduce(s);
    if (tid == 0) rp[b] = t * (1.0f / (float)(BB * DD));
  }

  if (b < 256) {
    const float S = 1024.0f / 65535.0f;
    int idx = b * 256 + tid;
    int j = idx >> 4;
    int l = idx & 15;
    float m = zm[idx];
    float lv = zlv[idx];
    float inv = EXP2(-lv * LOG2E_F);           // e^{-lv}
    float a = -0.5f * LOG2E_F * inv;
    float c2 = -0.5f * LOG2E_F * (lv + LOG2PI_F);
    coef[j * 48 + l]      = a * S;
    coef[j * 48 + 16 + l] = -2.0f * a * m * S;
    coef[j * 48 + 32 + l] = (fmaf(a, m * m, c2) + OFFC) * S;

    float kls = m * m + EXP2(lv * LOG2E_F) - lv - 1.0f;
    float s = block_reduce(kls);
    if (tid == 0) klp[b] = s * (0.5f / (float)BB);
  }
}

// ---------------------------------------------------------------------------
// Kernel B: TC partial sums. R10 numerics; coef staged in LDS (6 KB/block),
// read as wave-uniform ds_read_b128 broadcasts. R11's spill bug fixed by
// consuming each float4 immediately (l in groups of 4) — live set ~50 VGPRs,
// fits the 64-VGPR cap of (256,8) without scratch.
// ---------------------------------------------------------------------------
template <int CHUNK>
__global__ __launch_bounds__(256, 8) void tc_kernel(
    const float* __restrict__ z, const float* __restrict__ coef,
    float* __restrict__ partial) {
  __shared__ float lcoef[CHUNK * 48];
  const int tid = threadIdx.x;
  const int i = blockIdx.x * 256 + tid;  // this lane's row
  const int j0 = blockIdx.y * CHUNK;
  // w = js*65535*8192 - 2^23*(16*OFFC - BIASF)  ==  2^23*(sum_l lp2 + BIASF)
  const float JMUL = 65535.0f * 8192.0f;
  const float JK   = -SCALE23 * (16.0f * OFFC - BIASF);

  // Stage this block's coef chunk into LDS (coalesced float4 loads).
  {
    const float4* g4 = (const float4*)(coef + (size_t)j0 * 48);
    float4* l4 = (float4*)lcoef;
    for (int t = tid; t < (CHUNK * 48) / 4; t += 256) l4[t] = g4[t];
  }

  float zv[16];
  const float4* zp = (const float4*)(z + i * 16);
#pragma unroll
  for (int q = 0; q < 4; ++q) {
    float4 v = zp[q];
    zv[4 * q] = v.x; zv[4 * q + 1] = v.y; zv[4 * q + 2] = v.z; zv[4 * q + 3] = v.w;
  }

  union HU { unsigned u; __half2 h; };
  __half2 accH[8];
#pragma unroll
  for (int p = 0; p < 8; ++p) { HU t; t.u = 0u; accH[p] = t.h; }
  float accJ = 0.0f;

  __syncthreads();

  const float* cp = lcoef;
#pragma unroll 2
  for (int j = 0; j < CHUNK; ++j) {
    float js = 0.0f;
#pragma unroll
    for (int q = 0; q < 4; ++q) {
      // 3x ds_read_b128, consumed immediately (no long-lived arrays)
      float4 va = *(const float4*)(cp + 4 * q);
      float4 vb = *(const float4*)(cp + 16 + 4 * q);
      float4 vc = *(const float4*)(cp + 32 + 4 * q);
      float lp0 = fmaf(fmaf(va.x, zv[4 * q + 0], vb.x), zv[4 * q + 0], vc.x);
      float lp1 = fmaf(fmaf(va.y, zv[4 * q + 1], vb.y), zv[4 * q + 1], vc.y);
      float lp2 = fmaf(fmaf(va.z, zv[4 * q + 2], vb.z), zv[4 * q + 2], vc.z);
      float lp3 = fmaf(fmaf(va.w, zv[4 * q + 3], vb.w), zv[4 * q + 3], vc.w);
      HU t0, t1;
      asm("v_cvt_pknorm_u16_f32 %0, %1, %2"
          : "=v"(t0.u) : "v"(lp0), "v"(lp1));
      asm("v_cvt_pknorm_u16_f32 %0, %1, %2"
          : "=v"(t1.u) : "v"(lp2), "v"(lp3));
      accH[2 * q]     = __hadd2(accH[2 * q], t0.h);
      accH[2 * q + 1] = __hadd2(accH[2 * q + 1], t1.h);
      js += (lp0 + lp1) + (lp2 + lp3);
    }
    float w = fmaf(js, JMUL, JK);
    unsigned u;
    asm("v_cvt_u32_f32 %0, %1" : "=v"(u) : "v"(w));  // negatives saturate to 0
    accJ += __uint_as_float(u);
    cp += 48;
  }

  float* base = partial + ((size_t)blockIdx.y * 17) * BB + i;
#pragma unroll
  for (int p = 0; p < 8; ++p) {
    // accH halves hold sum_j 2^(lp2+8); 2^-8 rescale to true exp2 sums
    base[(size_t)(2 * p) * BB]     = 0.00390625f * __low2float(accH[p]);
    base[(size_t)(2 * p + 1) * BB] = 0.00390625f * __high2float(accH[p]);
  }
  base[(size_t)16 * BB] = accJ;
}

// ---------------------------------------------------------------------------
// Kernel C: reduce partials over chunks. grid (16, 17) = 272 blocks.
// ---------------------------------------------------------------------------
__global__ __launch_bounds__(256) void reduce_kernel(
    const float* __restrict__ partial, float* __restrict__ reduced, int nc) {
  const int i = blockIdx.x * 256 + threadIdx.x;
  const int k = blockIdx.y;
  const float* p = partial + (size_t)k * BB + i;
  const size_t cstride = (size_t)17 * BB;
  float s0 = 0.0f, s1 = 0.0f, s2 = 0.0f, s3 = 0.0f;
  int c = 0;
  for (; c + 4 <= nc; c += 4) {
    s0 += p[(size_t)(c + 0) * cstride];
    s1 += p[(size_t)(c + 1) * cstride];
    s2 += p[(size_t)(c + 2) * cstride];
    s3 += p[(size_t)(c + 3) * cstride];
  }
  for (; c < nc; ++c) s0 += p[(size_t)c * cstride];
  reduced[(size_t)k * BB + i] = (s0 + s1) + (s2 + s3);
}

// ---------------------------------------------------------------------------
// Kernel D: logs + fold recon/KL partials into out[0] (zeroed by kernel A).
// ---------------------------------------------------------------------------
__global__ __launch_bounds__(256) void final_kernel(
    const float* __restrict__ reduced, const float* __restrict__ rp,
    const float* __restrict__ klp, float* __restrict__ out) {
  const int tid = threadIdx.x;
  const int i = blockIdx.x * 256 + tid;
  float lg = LOG2(reduced[(size_t)16 * BB + i]);  // log2 S_joint
#pragma unroll
  for (int k = 0; k < 16; ++k) lg -= LOG2(reduced[(size_t)k * BB + i]);
  float t = lg * (LN2_F / (float)BB);
  if (blockIdx.x == 0) {
#pragma unroll
    for (int q = 0; q < 8; ++q) t += rp[tid + 256 * q];  // 2048 recon partials
    t += klp[tid];
  }
  float s = block_reduce(t);
  if (tid == 0) atomicAdd(out, s);
}

extern "C" void kernel_launch(void* const* d_in, const int* in_sizes, int n_in,
                              void* d_out, int out_size, void* d_ws, size_t ws_size,
                              hipStream_t stream) {
  const float* data  = (const float*)d_in[0];
  const float* recon = (const float*)d_in[1];
  const float* z     = (const float*)d_in[2];
  const float* zm    = (const float*)d_in[3];
  const float* zlv   = (const float*)d_in[4];
  float* out = (float*)d_out;
  float* ws  = (float*)d_ws;

  // nc=128 (CHUNK=32) if the partial buffer fits, else nc=64 (CHUNK=64).
  int nc = 128;
  if (((size_t)PART_F + (size_t)nc * 17 * BB) * 4 > ws_size) nc = 64;

  float* coef = ws + COEF_F;
  float* rp   = ws + RP_F;
  float* klp  = ws + KLP_F;
  float* red  = ws + RED_F;
  float* part = ws + PART_F;

  hipLaunchKernelGGL(prep_recon_kernel, dim3(2048), dim3(256), 0, stream,
                     reinterpret_cast<const float4*>(data),
                     reinterpret_cast<const float4*>(recon),
                     zm, zlv, coef, rp, klp, out);
  if (nc == 128) {
    hipLaunchKernelGGL(tc_kernel<32>, dim3(16, 128), dim3(256), 0, stream,
                       z, coef, part);
  } else {
    hipLaunchKernelGGL(tc_kernel<64>, dim3(16, 64), dim3(256), 0, stream,
                       z, coef, part);
  }
  hipLaunchKernelGGL(reduce_kernel, dim3(BB / 256, 17), dim3(256), 0, stream,
                     part, red, nc);
  hipLaunchKernelGGL(final_kernel, dim3(BB / 256), dim3(256), 0, stream,
                     red, rp, klp, out);
}